// Round 6
// baseline (92.335 us; speedup 1.0000x reference)
//
#include <hip/hip_runtime.h>
#include <hip/hip_bf16.h>

typedef __attribute__((ext_vector_type(8))) short bf16x8;
typedef __attribute__((ext_vector_type(4))) float f32x4;

#define N_TOT 8192
#define B_IN  4096
#define D_K   256
#define NPANEL 32   // 8192 / 256
#define NBLK  528   // NPANEL*(NPANEL+1)/2

typedef __attribute__((address_space(3))) unsigned int lds_uint;
typedef __attribute__((address_space(1))) const unsigned int glob_uint;

__device__ __forceinline__ unsigned short f2bf(float x) {
  unsigned u = __float_as_uint(x);
  u = (u + 0x7FFFu + ((u >> 16) & 1u)) >> 16;
  return (unsigned short)u;
}

__global__ void zero_kernel(int* __restrict__ cnt) {
  int i = blockIdx.x * 256 + threadIdx.x;
  if (i < 1024) cnt[i] = 0;
}

// Normalize each (b,v) row, write bf16 X in anchor order (n = v*B + b), fill labN, histogram cnt.
__global__ void norm_kernel(const float* __restrict__ feat,
                            const int* __restrict__ labels,
                            unsigned short* __restrict__ X,
                            int* __restrict__ labN,
                            int* __restrict__ cnt) {
  int n = blockIdx.x * 4 + (threadIdx.x >> 6);
  int l = threadIdx.x & 63;
  int b = n & (B_IN - 1);
  int v = n >> 12;
  const float4 f = *reinterpret_cast<const float4*>(feat + (size_t)(b * 2 + v) * D_K + l * 4);
  float s = f.x * f.x + f.y * f.y + f.z * f.z + f.w * f.w;
#pragma unroll
  for (int m = 1; m < 64; m <<= 1) s += __shfl_xor(s, m);
  float scale = 1.0f / fmaxf(sqrtf(s), 1e-12f);
  ushort4 o;
  o.x = f2bf(f.x * scale);
  o.y = f2bf(f.y * scale);
  o.z = f2bf(f.z * scale);
  o.w = f2bf(f.w * scale);
  *reinterpret_cast<ushort4*>(X + (size_t)n * D_K + l * 4) = o;
  if (l == 0) {
    int lb = labels[b];
    labN[n] = lb;
    if (n < B_IN) atomicAdd(&cnt[lb], 1);  // integer atomic: deterministic
  }
}

// Main: 528 blocks = upper-triangle panel pairs (pi<=pj) of 256x256 tiles.
// 512 threads = 8 waves; wave w owns rows [pi*256 + w*32, +32): A in 64 VGPRs.
// B cols streamed: 256 cols in 4 tiles of 64 via global_load_lds, 2x32KB dbuf.
// Row credit -> register partials (slot pj). Col credit (pi!=pj): per-jt column
// sums via shfl + per-wave LDS slots, flushed next jt (slot pi). Deterministic.
__global__ __launch_bounds__(512, 1) void main_kernel(const unsigned short* __restrict__ X,
                                                      const int* __restrict__ labN,
                                                      float* __restrict__ SpA,
                                                      float* __restrict__ PpA) {
  __shared__ __align__(16) char Bs[2][32768];
  __shared__ float colS[2][8][64];
  __shared__ float colP[2][8][64];
  const int tid = threadIdx.x;
  const int l = tid & 63, w = tid >> 6;
  const int lm = l & 15, lh = l >> 4;

  // triangle decode: row pi has (32-pi) blocks
  int pi = 0, bres = blockIdx.x;
  while (bres >= NPANEL - pi) { bres -= NPANEL - pi; ++pi; }
  const int pj = pi + bres;
  const bool doCol = (pi != pj);
  const int rbase = pi * 256;
  const int cbase = pj * 256;
  const int wrow = rbase + w * 32;

  // stage jt=0 into Bs[0]; source pre-swizzled (slot e -> e^(row&7)), LDS linear
  {
    char* buf = &Bs[0][0];
#pragma unroll
    for (int i = 0; i < 4; ++i) {
      int c = i * 512 + tid;  // int4 slots 0..2047
      int row = c >> 5;
      int c16s = (c & 31) ^ (row & 7);
      const int4* g = reinterpret_cast<const int4*>(X + (size_t)(cbase + row) * D_K) + c16s;
      char* s = buf + (size_t)(i * 512 + (w << 6)) * 16;  // wave-uniform base
      __builtin_amdgcn_global_load_lds((glob_uint*)g, (lds_uint*)s, 16, 0, 0);
    }
  }

  // A fragments: rows wrow + fi*16 + lm, elems kk*32 + lh*8 .. +7
  bf16x8 a[2][8];
#pragma unroll
  for (int fi = 0; fi < 2; ++fi)
#pragma unroll
    for (int kk = 0; kk < 8; ++kk)
      a[fi][kk] = *reinterpret_cast<const bf16x8*>(
          X + (size_t)(wrow + fi * 16 + lm) * D_K + kk * 32 + lh * 8);

  int labR[2][4];
#pragma unroll
  for (int fi = 0; fi < 2; ++fi)
#pragma unroll
    for (int r = 0; r < 4; ++r) labR[fi][r] = labN[wrow + fi * 16 + lh * 4 + r];

  float S[2][4] = {};
  float Pv[2][4] = {};

  __syncthreads();  // jt=0 stage drained

  for (int jt = 0; jt < 4; ++jt) {
    const int cur = jt & 1;

    // flush previous jt's column credits (written before last barrier)
    if (doCol && jt > 0 && tid < 128) {
      int cc = tid & 63;
      const float(*src)[64] = (tid < 64) ? colS[cur ^ 1] : colP[cur ^ 1];
      float s = 0.f;
#pragma unroll
      for (int ww = 0; ww < 8; ++ww) s += src[ww][cc];
      int cg = cbase + (jt - 1) * 64 + cc;
      if (tid < 64) SpA[pi * N_TOT + cg] = s;
      else PpA[pi * N_TOT + cg] = s;
    }

    // stage jt+1 into the other buffer
    if (jt < 3) {
      char* buf = &Bs[cur ^ 1][0];
      const int col0 = cbase + (jt + 1) * 64;
#pragma unroll
      for (int i = 0; i < 4; ++i) {
        int c = i * 512 + tid;
        int row = c >> 5;
        int c16s = (c & 31) ^ (row & 7);
        const int4* g = reinterpret_cast<const int4*>(X + (size_t)(col0 + row) * D_K) + c16s;
        char* s = buf + (size_t)(i * 512 + (w << 6)) * 16;
        __builtin_amdgcn_global_load_lds((glob_uint*)g, (lds_uint*)s, 16, 0, 0);
      }
    }

    const char* bufc = &Bs[cur][0];
#pragma unroll
    for (int sub = 0; sub < 2; ++sub) {
      f32x4 acc[2][2];
#pragma unroll
      for (int fi = 0; fi < 2; ++fi) {
        acc[fi][0] = (f32x4){0.f, 0.f, 0.f, 0.f};
        acc[fi][1] = (f32x4){0.f, 0.f, 0.f, 0.f};
      }
      const int lrow0 = sub * 32 + lm;
      const int lrow1 = lrow0 + 16;
      const int ba0 = lrow0 * 512, sw0 = (lrow0 & 7) << 4;
      const int ba1 = lrow1 * 512, sw1 = (lrow1 & 7) << 4;
#pragma unroll
      for (int kk = 0; kk < 8; ++kk) {
        int ko = kk * 64 + lh * 16;
        bf16x8 b0 = *reinterpret_cast<const bf16x8*>(bufc + ba0 + (ko ^ sw0));
        bf16x8 b1 = *reinterpret_cast<const bf16x8*>(bufc + ba1 + (ko ^ sw1));
#pragma unroll
        for (int fi = 0; fi < 2; ++fi) {
          acc[fi][0] = __builtin_amdgcn_mfma_f32_16x16x32_bf16(a[fi][kk], b0, acc[fi][0], 0, 0, 0);
          acc[fi][1] = __builtin_amdgcn_mfma_f32_16x16x32_bf16(a[fi][kk], b1, acc[fi][1], 0, 0, 0);
        }
      }
      // epilogue. exp(2v-2) = exp2(c*v - c), c = 2/ln2. Self terms removed in reduce.
      const int cg0 = cbase + jt * 64 + sub * 32 + lm;
      const int labC0 = labN[cg0];
      const int labC1 = labN[cg0 + 16];
      float ce[2] = {0.f, 0.f}, cp[2] = {0.f, 0.f};
#pragma unroll
      for (int fi = 0; fi < 2; ++fi)
#pragma unroll
        for (int fj = 0; fj < 2; ++fj) {
          const int labC = (fj == 0) ? labC0 : labC1;
#pragma unroll
          for (int r = 0; r < 4; ++r) {
            float v = acc[fi][fj][r];
            float ev = exp2f(fmaf(v, 2.8853900817779268f, -2.8853900817779268f));
            float mv = (labR[fi][r] == labC) ? v : 0.f;
            S[fi][r] += ev;
            Pv[fi][r] += mv;
            ce[fj] += ev;
            cp[fj] += mv;
          }
        }
      if (doCol) {
#pragma unroll
        for (int fj = 0; fj < 2; ++fj) {
          float e = ce[fj], p = cp[fj];
          e += __shfl_xor(e, 16);
          e += __shfl_xor(e, 32);
          p += __shfl_xor(p, 16);
          p += __shfl_xor(p, 32);
          if (lh == 0) {
            colS[cur][w][sub * 32 + fj * 16 + lm] = e;
            colP[cur][w][sub * 32 + fj * 16 + lm] = p;
          }
        }
      }
    }
    __syncthreads();
  }

  // final column flush (jt=3 wrote buffer 1)
  if (doCol && tid < 128) {
    int cc = tid & 63;
    const float(*src)[64] = (tid < 64) ? colS[1] : colP[1];
    float s = 0.f;
#pragma unroll
    for (int ww = 0; ww < 8; ++ww) s += src[ww][cc];
    int cg = cbase + 3 * 64 + cc;
    if (tid < 64) SpA[pi * N_TOT + cg] = s;
    else PpA[pi * N_TOT + cg] = s;
  }

  // row credit: reduce across the 16 lm lanes; slot pj
#pragma unroll
  for (int fi = 0; fi < 2; ++fi)
#pragma unroll
    for (int r = 0; r < 4; ++r) {
      float s = S[fi][r], p = Pv[fi][r];
#pragma unroll
      for (int m = 1; m < 16; m <<= 1) {
        s += __shfl_xor(s, m);
        p += __shfl_xor(p, m);
      }
      if (lm == 0) {
        int row = wrow + fi * 16 + lh * 4 + r;
        SpA[pj * N_TOT + row] = s;
        PpA[pj * N_TOT + row] = p;
      }
    }
}

__global__ void reduce1_kernel(const float* __restrict__ Sp, const float* __restrict__ Pp,
                               const int* __restrict__ labN, const int* __restrict__ cnt,
                               float* __restrict__ partial) {
  __shared__ float red[4];
  int tid = threadIdx.x;
  int n = blockIdx.x * 256 + tid;  // 32 blocks x 256 = 8192
  float S = 0.f, Pv = 0.f;
#pragma unroll
  for (int s = 0; s < NPANEL; ++s) {
    S += Sp[s * N_TOT + n];
    Pv += Pp[s * N_TOT + n];
  }
  S -= 1.0f;                   // remove self exp term (exp(2*selfdot-2) ~= 1)
  float P = 2.0f * Pv - 2.0f;  // remove self logit term (~= 2)
  float np = (float)(2 * cnt[labN[n]] - 1);
  float acc = logf(S) + 2.0f - P / np;
#pragma unroll
  for (int m = 1; m < 64; m <<= 1) acc += __shfl_xor(acc, m);
  if ((tid & 63) == 0) red[tid >> 6] = acc;
  __syncthreads();
  if (tid == 0) partial[blockIdx.x] = red[0] + red[1] + red[2] + red[3];
}

__global__ void reduce2_kernel(const float* __restrict__ partial, float* __restrict__ out) {
  int tid = threadIdx.x;  // 64
  float v = (tid < 32) ? partial[tid] : 0.f;
#pragma unroll
  for (int m = 1; m < 64; m <<= 1) v += __shfl_xor(v, m);
  if (tid == 0) out[0] = v * (1.0f / (float)N_TOT);
}

extern "C" void kernel_launch(void* const* d_in, const int* in_sizes, int n_in,
                              void* d_out, int out_size, void* d_ws, size_t ws_size,
                              hipStream_t stream) {
  const float* feat = (const float*)d_in[0];
  const int* labels = (const int*)d_in[1];
  char* ws = (char*)d_ws;
  unsigned short* X = (unsigned short*)ws;   // 4 MB
  int* labN = (int*)(ws + 4194304);          // 32 KB
  int* cnt = (int*)(ws + 4227072);           // 4 KB
  float* Sp = (float*)(ws + 4231168);        // 32*8192*4 = 1 MB
  float* Pp = (float*)(ws + 5279744);        // 1 MB
  float* partial = (float*)(ws + 6328320);   // 128 B
  float* out = (float*)d_out;

  zero_kernel<<<4, 256, 0, stream>>>(cnt);
  norm_kernel<<<2048, 256, 0, stream>>>(feat, labels, X, labN, cnt);
  main_kernel<<<NBLK, 512, 0, stream>>>(X, labN, Sp, Pp);
  reduce1_kernel<<<32, 256, 0, stream>>>(Sp, Pp, labN, cnt, partial);
  reduce2_kernel<<<1, 64, 0, stream>>>(partial, out);
}

// Round 7
// 88.435 us; speedup vs baseline: 1.0441x; 1.0441x over previous
//
#include <hip/hip_runtime.h>
#include <hip/hip_bf16.h>

typedef __attribute__((ext_vector_type(8))) short bf16x8;
typedef __attribute__((ext_vector_type(4))) float f32x4;

#define N_TOT 8192
#define B_IN  4096
#define D_K   256
#define NSPLIT 32   // col splits of 256
#define NPANEL 64   // row panels of 128

typedef __attribute__((address_space(3))) unsigned int lds_uint;
typedef __attribute__((address_space(1))) const unsigned int glob_uint;

__device__ __forceinline__ unsigned short f2bf(float x) {
  unsigned u = __float_as_uint(x);
  u = (u + 0x7FFFu + ((u >> 16) & 1u)) >> 16;
  return (unsigned short)u;
}

__global__ void zero_kernel(int* __restrict__ cnt) {
  int i = blockIdx.x * 256 + threadIdx.x;
  if (i < 1024) cnt[i] = 0;
}

// Normalize each (b,v) row, write bf16 X in anchor order (n = v*B + b), fill labN, histogram cnt.
__global__ void norm_kernel(const float* __restrict__ feat,
                            const int* __restrict__ labels,
                            unsigned short* __restrict__ X,
                            int* __restrict__ labN,
                            int* __restrict__ cnt) {
  int n = blockIdx.x * 4 + (threadIdx.x >> 6);
  int l = threadIdx.x & 63;
  int b = n & (B_IN - 1);
  int v = n >> 12;
  const float4 f = *reinterpret_cast<const float4*>(feat + (size_t)(b * 2 + v) * D_K + l * 4);
  float s = f.x * f.x + f.y * f.y + f.z * f.z + f.w * f.w;
#pragma unroll
  for (int m = 1; m < 64; m <<= 1) s += __shfl_xor(s, m);
  float scale = 1.0f / fmaxf(sqrtf(s), 1e-12f);
  ushort4 o;
  o.x = f2bf(f.x * scale);
  o.y = f2bf(f.y * scale);
  o.z = f2bf(f.z * scale);
  o.w = f2bf(f.w * scale);
  *reinterpret_cast<ushort4*>(X + (size_t)n * D_K + l * 4) = o;
  if (l == 0) {
    int lb = labels[b];
    labN[n] = lb;
    if (n < B_IN) atomicAdd(&cnt[lb], 1);  // integer atomic: deterministic
  }
}

// Main: 2048 blocks = 64 row-panels (128 rows) x 32 col-splits (256 cols).
// 256 threads = 4 waves; wave w owns rows [rbase + w*32, +32): A in 64 VGPRs.
// Cols streamed as 8 tiles of 32 via global_load_lds into 2x16KB LDS dbuf.
// Small blocks -> 4 blocks/CU resident -> cross-block latency hiding.
__global__ __launch_bounds__(256, 2) void main_kernel(const unsigned short* __restrict__ X,
                                                      const int* __restrict__ labN,
                                                      float* __restrict__ SpA,
                                                      float* __restrict__ PpA) {
  __shared__ __align__(16) char Bs[2][16384];
  const int tid = threadIdx.x;
  const int l = tid & 63, w = tid >> 6;
  const int lm = l & 15, lh = l >> 4;
  const int panel = blockIdx.x >> 5;  // 64 panels of 128 rows
  const int split = blockIdx.x & 31;  // 32 splits of 256 cols
  const int rbase = panel * 128;
  const int cbase = split * 256;
  const int wrow = rbase + w * 32;

  // stage jt=0 into Bs[0]; source pre-swizzled (slot e -> e^(row&7)), LDS linear.
  // tile = 32 rows(cols of C) x 512B = 1024 int4 slots; 4 issues x 256 lanes.
  {
    char* buf = &Bs[0][0];
#pragma unroll
    for (int i = 0; i < 4; ++i) {
      int c = i * 256 + tid;
      int row = c >> 5;
      int c16s = (c & 31) ^ (row & 7);
      const int4* g = reinterpret_cast<const int4*>(X + (size_t)(cbase + row) * D_K) + c16s;
      char* s = buf + (size_t)(i * 256 + (w << 6)) * 16;  // wave-uniform base
      __builtin_amdgcn_global_load_lds((glob_uint*)g, (lds_uint*)s, 16, 0, 0);
    }
  }

  // A fragments: rows wrow + fi*16 + lm, elems kk*32 + lh*8 .. +7
  bf16x8 a[2][8];
#pragma unroll
  for (int fi = 0; fi < 2; ++fi)
#pragma unroll
    for (int kk = 0; kk < 8; ++kk)
      a[fi][kk] = *reinterpret_cast<const bf16x8*>(
          X + (size_t)(wrow + fi * 16 + lm) * D_K + kk * 32 + lh * 8);

  int labR[2][4];
#pragma unroll
  for (int fi = 0; fi < 2; ++fi)
#pragma unroll
    for (int r = 0; r < 4; ++r) labR[fi][r] = labN[wrow + fi * 16 + lh * 4 + r];

  float S[2][4] = {};
  float Pv[2][4] = {};

  __syncthreads();  // jt=0 stage drained

  for (int jt = 0; jt < 8; ++jt) {
    const int cur = jt & 1;
    // stage jt+1 into the other buffer (its readers passed the previous barrier)
    if (jt < 7) {
      char* buf = &Bs[cur ^ 1][0];
      const int col0 = cbase + (jt + 1) * 32;
#pragma unroll
      for (int i = 0; i < 4; ++i) {
        int c = i * 256 + tid;
        int row = c >> 5;
        int c16s = (c & 31) ^ (row & 7);
        const int4* g = reinterpret_cast<const int4*>(X + (size_t)(col0 + row) * D_K) + c16s;
        char* s = buf + (size_t)(i * 256 + (w << 6)) * 16;
        __builtin_amdgcn_global_load_lds((glob_uint*)g, (lds_uint*)s, 16, 0, 0);
      }
    }

    const char* bufc = &Bs[cur][0];
    f32x4 acc[2][2];
#pragma unroll
    for (int fi = 0; fi < 2; ++fi) {
      acc[fi][0] = (f32x4){0.f, 0.f, 0.f, 0.f};
      acc[fi][1] = (f32x4){0.f, 0.f, 0.f, 0.f};
    }
    const int ba0 = lm * 512, sw0 = (lm & 7) << 4;
    const int ba1 = (lm + 16) * 512;  // same low-3 bits -> same swizzle
#pragma unroll
    for (int kk = 0; kk < 8; ++kk) {
      int ko = (kk * 64 + lh * 16) ^ sw0;
      bf16x8 b0 = *reinterpret_cast<const bf16x8*>(bufc + ba0 + ko);
      bf16x8 b1 = *reinterpret_cast<const bf16x8*>(bufc + ba1 + ko);
#pragma unroll
      for (int fi = 0; fi < 2; ++fi) {
        acc[fi][0] = __builtin_amdgcn_mfma_f32_16x16x32_bf16(a[fi][kk], b0, acc[fi][0], 0, 0, 0);
        acc[fi][1] = __builtin_amdgcn_mfma_f32_16x16x32_bf16(a[fi][kk], b1, acc[fi][1], 0, 0, 0);
      }
    }
    // epilogue: S += exp(2v-2) = exp2(c*v - c) over ALL cols; Pv += v on label match.
    // Self terms removed analytically in the reduce.
    const int cg0 = cbase + jt * 32 + lm;
    const int labC0 = labN[cg0];
    const int labC1 = labN[cg0 + 16];
#pragma unroll
    for (int fi = 0; fi < 2; ++fi)
#pragma unroll
      for (int fj = 0; fj < 2; ++fj) {
        const int labC = (fj == 0) ? labC0 : labC1;
#pragma unroll
        for (int r = 0; r < 4; ++r) {
          float v = acc[fi][fj][r];
          S[fi][r] += exp2f(fmaf(v, 2.8853900817779268f, -2.8853900817779268f));
          Pv[fi][r] += (labR[fi][r] == labC) ? v : 0.f;
        }
      }
    __syncthreads();
  }

  // row credit: reduce across the 16 lm lanes; one writer per (split,row)
#pragma unroll
  for (int fi = 0; fi < 2; ++fi)
#pragma unroll
    for (int r = 0; r < 4; ++r) {
      float s = S[fi][r], p = Pv[fi][r];
#pragma unroll
      for (int m = 1; m < 16; m <<= 1) {
        s += __shfl_xor(s, m);
        p += __shfl_xor(p, m);
      }
      if (lm == 0) {
        int row = wrow + fi * 16 + lh * 4 + r;
        SpA[split * N_TOT + row] = s;
        PpA[split * N_TOT + row] = p;
      }
    }
}

__global__ void reduce1_kernel(const float* __restrict__ Sp, const float* __restrict__ Pp,
                               const int* __restrict__ labN, const int* __restrict__ cnt,
                               float* __restrict__ partial) {
  __shared__ float red[4];
  int tid = threadIdx.x;
  int n = blockIdx.x * 256 + tid;  // 32 blocks x 256 = 8192
  float S = 0.f, Pv = 0.f;
#pragma unroll
  for (int s = 0; s < NSPLIT; ++s) {
    S += Sp[s * N_TOT + n];
    Pv += Pp[s * N_TOT + n];
  }
  S -= 1.0f;                   // remove self exp term (exp(2*selfdot-2) ~= 1)
  float P = 2.0f * Pv - 2.0f;  // remove self logit term (~= 2)
  float np = (float)(2 * cnt[labN[n]] - 1);
  float acc = logf(S) + 2.0f - P / np;
#pragma unroll
  for (int m = 1; m < 64; m <<= 1) acc += __shfl_xor(acc, m);
  if ((tid & 63) == 0) red[tid >> 6] = acc;
  __syncthreads();
  if (tid == 0) partial[blockIdx.x] = red[0] + red[1] + red[2] + red[3];
}

__global__ void reduce2_kernel(const float* __restrict__ partial, float* __restrict__ out) {
  int tid = threadIdx.x;  // 64
  float v = (tid < 32) ? partial[tid] : 0.f;
#pragma unroll
  for (int m = 1; m < 64; m <<= 1) v += __shfl_xor(v, m);
  if (tid == 0) out[0] = v * (1.0f / (float)N_TOT);
}

extern "C" void kernel_launch(void* const* d_in, const int* in_sizes, int n_in,
                              void* d_out, int out_size, void* d_ws, size_t ws_size,
                              hipStream_t stream) {
  const float* feat = (const float*)d_in[0];
  const int* labels = (const int*)d_in[1];
  char* ws = (char*)d_ws;
  unsigned short* X = (unsigned short*)ws;   // 4 MB
  int* labN = (int*)(ws + 4194304);          // 32 KB
  int* cnt = (int*)(ws + 4227072);           // 4 KB
  float* Sp = (float*)(ws + 4231168);        // 32*8192*4 = 1 MB
  float* Pp = (float*)(ws + 5279744);        // 1 MB
  float* partial = (float*)(ws + 6328320);   // 128 B
  float* out = (float*)d_out;

  zero_kernel<<<4, 256, 0, stream>>>(cnt);
  norm_kernel<<<2048, 256, 0, stream>>>(feat, labels, X, labN, cnt);
  main_kernel<<<NPANEL * NSPLIT, 256, 0, stream>>>(X, labN, Sp, Pp);
  reduce1_kernel<<<32, 256, 0, stream>>>(Sp, Pp, labN, cnt, partial);
  reduce2_kernel<<<1, 64, 0, stream>>>(partial, out);
}